// Round 1
// baseline (1202.172 us; speedup 1.0000x reference)
//
#include <hip/hip_runtime.h>

#define T_STEPS 1000
#define BATCH   64
#define FIN     128
#define HID     512
#define NOUT    32

// ---------------- prep: weight transposes ----------------
__global__ void prep_transpose(const float* __restrict__ w_rec,
                               const float* __restrict__ w_out,
                               float* __restrict__ wrecT,
                               float* __restrict__ woutT) {
    int idx = blockIdx.x * blockDim.x + threadIdx.x;
    if (idx < HID * HID) {
        int j = idx / HID, h = idx % HID;
        wrecT[h * HID + j] = w_rec[idx];          // wrecT[h][j] = w_rec[j][h]
    }
    if (idx < NOUT * HID) {
        int o = idx / HID, h = idx % HID;
        woutT[h * NOUT + o] = w_out[idx];         // woutT[h][o] = w_out[o][h]
    }
}

// ---------------- prep: XWin[tb][h] = sum_k x[tb][k] * w_in[h][k] ----------------
#define GTM 128
#define GTN 128
#define GKC 32

__global__ __launch_bounds__(256)
void xwin_gemm(const float* __restrict__ x, const float* __restrict__ w_in,
               float* __restrict__ xwin) {
    __shared__ float xs[GKC][GTM + 4];
    __shared__ float ws[GKC][GTN + 4];
    const int tid = threadIdx.x;
    const int tb_base = blockIdx.x * GTM;
    const int h_base  = blockIdx.y * GTN;
    const int tx = tid & 15, ty = tid >> 4;

    float acc[8][8];
#pragma unroll
    for (int i = 0; i < 8; ++i)
#pragma unroll
        for (int j = 0; j < 8; ++j) acc[i][j] = 0.f;

    for (int kc = 0; kc < FIN; kc += GKC) {
#pragma unroll
        for (int q = 0; q < 4; ++q) {
            int li  = tid * 4 + q;        // 0..1023 -> 128 rows x 8 float4
            int row = li >> 3, c4 = li & 7;
            float4 v = *(const float4*)&x[(size_t)(tb_base + row) * FIN + kc + c4 * 4];
            xs[c4*4+0][row] = v.x; xs[c4*4+1][row] = v.y;
            xs[c4*4+2][row] = v.z; xs[c4*4+3][row] = v.w;
            float4 w = *(const float4*)&w_in[(size_t)(h_base + row) * FIN + kc + c4 * 4];
            ws[c4*4+0][row] = w.x; ws[c4*4+1][row] = w.y;
            ws[c4*4+2][row] = w.z; ws[c4*4+3][row] = w.w;
        }
        __syncthreads();
#pragma unroll
        for (int k = 0; k < GKC; ++k) {
            float4 a0 = *(const float4*)&xs[k][tx * 8];
            float4 a1 = *(const float4*)&xs[k][tx * 8 + 4];
            float4 b0 = *(const float4*)&ws[k][ty * 8];
            float4 b1 = *(const float4*)&ws[k][ty * 8 + 4];
            float av[8] = {a0.x, a0.y, a0.z, a0.w, a1.x, a1.y, a1.z, a1.w};
            float bv[8] = {b0.x, b0.y, b0.z, b0.w, b1.x, b1.y, b1.z, b1.w};
#pragma unroll
            for (int i = 0; i < 8; ++i)
#pragma unroll
                for (int j = 0; j < 8; ++j)
                    acc[i][j] = fmaf(av[i], bv[j], acc[i][j]);
        }
        __syncthreads();
    }
#pragma unroll
    for (int i = 0; i < 8; ++i) {
        size_t tb = (size_t)tb_base + tx * 8 + i;
        float4 o0 = make_float4(acc[i][0], acc[i][1], acc[i][2], acc[i][3]);
        float4 o1 = make_float4(acc[i][4], acc[i][5], acc[i][6], acc[i][7]);
        *(float4*)&xwin[tb * HID + h_base + ty * 8]     = o0;
        *(float4*)&xwin[tb * HID + h_base + ty * 8 + 4] = o1;
    }
}

// ---------------- main sequential SNN scan: one block per batch element ----------------
// wr indexing: rec term for neuron `tid`, spike index `i`: wr[i*wrA + tid*wrB]
//   transposed  (wrecT): wrA=HID,  wrB=1
//   raw (w_rec):         wrA=1,    wrB=HID
// wo indexing analogous for readout.
template<int PRECOMP>
__global__ __launch_bounds__(512)
void snn_main(const float* __restrict__ xsrc,   // PRECOMP ? xwin[T,B,H] : x[T,B,F]
              const float* __restrict__ w_in,   // used when !PRECOMP
              const float* __restrict__ wr, int wrA, int wrB,
              const float* __restrict__ wo, int woA, int woB,
              const float* __restrict__ b_out,
              float* __restrict__ out) {
    const int b    = blockIdx.x;
    const int tid  = threadIdx.x;                // neuron index h
    const int lane = tid & 63;

    __shared__ int   s_list[2][HID];
    __shared__ int   s_cnt[2];
    __shared__ float s_xrow[2][FIN];             // only used when !PRECOMP

    if (tid < 2) s_cnt[tid] = 0;
    if (!PRECOMP && tid < FIN)
        s_xrow[0][tid] = xsrc[(size_t)b * FIN + tid];           // x[0][b][tid]
    float iin_reg = 0.f;
    if (PRECOMP) iin_reg = xsrc[(size_t)b * HID + tid];         // xwin[0][b][tid]
    __syncthreads();

    float v = 0.f, ic = 0.f, rho = 0.f, o_state = 0.f;
    const float bout_v = (tid < NOUT) ? b_out[tid] : 0.f;

    for (int t = 0; t < T_STEPS; ++t) {
        const int cur = t & 1, nxt = cur ^ 1;

        // prefetch next step's input projection early (hidden under this step)
        float iin_next = 0.f;
        if (PRECOMP) {
            int tn = (t + 1 < T_STEPS) ? (t + 1) : t;
            iin_next = xsrc[((size_t)tn * BATCH + b) * HID + tid];
        }

        float iin;
        if (PRECOMP) {
            iin = iin_reg;
        } else {
            float s0 = 0.f, s1 = 0.f, s2 = 0.f, s3 = 0.f;
#pragma unroll
            for (int kq = 0; kq < FIN / 4; ++kq) {
                float4 xv = *(const float4*)&s_xrow[cur][kq * 4];
                float4 wv = *(const float4*)&w_in[(size_t)tid * FIN + kq * 4];
                s0 = fmaf(xv.x, wv.x, s0);
                s1 = fmaf(xv.y, wv.y, s1);
                s2 = fmaf(xv.z, wv.z, s2);
                s3 = fmaf(xv.w, wv.w, s3);
            }
            iin = (s0 + s1) + (s2 + s3);
        }

        // ---- recurrent input from previous-step spikes (sparse gather) ----
        const int cn = s_cnt[cur];
        float r0 = 0.f, r1 = 0.f, r2 = 0.f, r3 = 0.f;
        int k = 0;
        for (; k + 4 <= cn; k += 4) {
            int i0 = s_list[cur][k],     i1 = s_list[cur][k + 1];
            int i2 = s_list[cur][k + 2], i3 = s_list[cur][k + 3];
            r0 += wr[(size_t)i0 * wrA + (size_t)tid * wrB];
            r1 += wr[(size_t)i1 * wrA + (size_t)tid * wrB];
            r2 += wr[(size_t)i2 * wrA + (size_t)tid * wrB];
            r3 += wr[(size_t)i3 * wrA + (size_t)tid * wrB];
        }
        for (; k < cn; ++k)
            r0 += wr[(size_t)s_list[cur][k] * wrA + (size_t)tid * wrB];
        const float rec = (r0 + r1) + (r2 + r3);

        // ---- LIF + refractory update (exact reference expression forms) ----
        const float v_dec = v + 0.1f * ((0.0f - v) + ic);
        const float i_dec = ic * 0.8f;
        float z      = (v_dec - 1.0f) > 0.0f ? 1.0f : 0.0f;
        float v_tmp  = (z != 0.0f) ? 0.0f : v_dec;
        const float refr = (rho > 0.0f) ? 1.0f : 0.0f;
        v   = (refr != 0.0f) ? v : v_tmp;
        z   = (refr != 0.0f) ? 0.0f : z;
        rho = (z != 0.0f) ? 5.0f : fmaxf(rho - refr, 0.0f);
        ic  = (i_dec + iin) + rec;

        // ---- build next spike list (ballot + 1 LDS atomic per wave) ----
        unsigned long long m = __ballot(z != 0.0f);
        int nsp = __popcll(m);
        int base = 0;
        if (lane == 0 && nsp) base = atomicAdd(&s_cnt[nxt], nsp);
        base = __shfl(base, 0);
        if (z != 0.0f) {
            int pos = base + __popcll(m & ((1ull << lane) - 1ull));
            s_list[nxt][pos] = tid;
        }
        __syncthreads();                          // list[nxt] complete

        // ---- readout: lin = z_new @ w_out.T + b_out; exp filter ----
        if (tid < NOUT) {
            const int c2 = s_cnt[nxt];
            float lin = 0.f;
            for (int kk = 0; kk < c2; ++kk)
                lin += wo[(size_t)s_list[nxt][kk] * woA + (size_t)tid * woB];
            lin += bout_v;
            o_state = o_state + 0.2231435511314f * (lin - o_state);
            out[((size_t)t * BATCH + b) * NOUT + tid] = o_state;
        }
        if (tid == 0) s_cnt[cur] = 0;             // reset for next step's build
        if (!PRECOMP && tid >= 128 && tid < 128 + FIN) {
            int tn = (t + 1 < T_STEPS) ? (t + 1) : t;
            s_xrow[nxt][tid - 128] = xsrc[((size_t)tn * BATCH + b) * FIN + (tid - 128)];
        }
        if (PRECOMP) iin_reg = iin_next;
        __syncthreads();                          // cnt reset + staging visible
    }
}

extern "C" void kernel_launch(void* const* d_in, const int* in_sizes, int n_in,
                              void* d_out, int out_size, void* d_ws, size_t ws_size,
                              hipStream_t stream) {
    const float* x     = (const float*)d_in[0];
    const float* w_in  = (const float*)d_in[1];
    const float* w_rec = (const float*)d_in[2];
    const float* w_out = (const float*)d_in[3];
    const float* b_out = (const float*)d_in[4];
    float* out = (float*)d_out;

    const size_t xwin_bytes  = (size_t)T_STEPS * BATCH * HID * sizeof(float); // 131 MB
    const size_t wrect_bytes = (size_t)HID * HID * sizeof(float);             // 1 MB
    const size_t woutt_bytes = (size_t)HID * NOUT * sizeof(float);            // 64 KB

    char* ws = (char*)d_ws;

    if (ws_size >= xwin_bytes + wrect_bytes + woutt_bytes) {
        float* xwin  = (float*)ws;
        float* wrecT = (float*)(ws + xwin_bytes);
        float* woutT = (float*)(ws + xwin_bytes + wrect_bytes);
        prep_transpose<<<(HID * HID + 255) / 256, 256, 0, stream>>>(w_rec, w_out, wrecT, woutT);
        dim3 g(T_STEPS * BATCH / GTM, HID / GTN);
        xwin_gemm<<<g, 256, 0, stream>>>(x, w_in, xwin);
        snn_main<1><<<BATCH, HID, 0, stream>>>(xwin, nullptr,
                                               wrecT, HID, 1,
                                               woutT, NOUT, 1,
                                               b_out, out);
    } else if (ws_size >= wrect_bytes + woutt_bytes) {
        float* wrecT = (float*)ws;
        float* woutT = (float*)(ws + wrect_bytes);
        prep_transpose<<<(HID * HID + 255) / 256, 256, 0, stream>>>(w_rec, w_out, wrecT, woutT);
        snn_main<0><<<BATCH, HID, 0, stream>>>(x, w_in,
                                               wrecT, HID, 1,
                                               woutT, NOUT, 1,
                                               b_out, out);
    } else {
        snn_main<0><<<BATCH, HID, 0, stream>>>(x, w_in,
                                               w_rec, 1, HID,
                                               w_out, 1, HID,
                                               b_out, out);
    }
}

// Round 2
// 1051.627 us; speedup vs baseline: 1.1432x; 1.1432x over previous
//
#include <hip/hip_runtime.h>

#define T_STEPS 1000
#define BATCH   64
#define FIN     128
#define HID     512
#define NOUT    32
#define ALPHA_F 0.2231435511314f

// ---------------- prep: weight transposes ----------------
__global__ void prep_transpose(const float* __restrict__ w_rec,
                               const float* __restrict__ w_out,
                               float* __restrict__ wrecT,
                               float* __restrict__ woutT) {
    int idx = blockIdx.x * blockDim.x + threadIdx.x;
    if (idx < HID * HID) {
        int j = idx / HID, h = idx % HID;
        wrecT[h * HID + j] = w_rec[idx];          // wrecT[h][j] = w_rec[j][h]
    }
    if (idx < NOUT * HID) {
        int o = idx / HID, h = idx % HID;
        woutT[h * NOUT + o] = w_out[idx];         // woutT[h][o] = w_out[o][h]
    }
}

// ---------------- prep: XWin[tb][h] = sum_k x[tb][k] * w_in[h][k] ----------------
#define GTM 128
#define GTN 128
#define GKC 32

__global__ __launch_bounds__(256)
void xwin_gemm(const float* __restrict__ x, const float* __restrict__ w_in,
               float* __restrict__ xwin) {
    __shared__ float xs[GKC][GTM + 4];
    __shared__ float ws[GKC][GTN + 4];
    const int tid = threadIdx.x;
    const int tb_base = blockIdx.x * GTM;
    const int h_base  = blockIdx.y * GTN;
    const int tx = tid & 15, ty = tid >> 4;

    float acc[8][8];
#pragma unroll
    for (int i = 0; i < 8; ++i)
#pragma unroll
        for (int j = 0; j < 8; ++j) acc[i][j] = 0.f;

    for (int kc = 0; kc < FIN; kc += GKC) {
#pragma unroll
        for (int q = 0; q < 4; ++q) {
            int li  = tid * 4 + q;
            int row = li >> 3, c4 = li & 7;
            float4 v = *(const float4*)&x[(size_t)(tb_base + row) * FIN + kc + c4 * 4];
            xs[c4*4+0][row] = v.x; xs[c4*4+1][row] = v.y;
            xs[c4*4+2][row] = v.z; xs[c4*4+3][row] = v.w;
            float4 w = *(const float4*)&w_in[(size_t)(h_base + row) * FIN + kc + c4 * 4];
            ws[c4*4+0][row] = w.x; ws[c4*4+1][row] = w.y;
            ws[c4*4+2][row] = w.z; ws[c4*4+3][row] = w.w;
        }
        __syncthreads();
#pragma unroll
        for (int k = 0; k < GKC; ++k) {
            float4 a0 = *(const float4*)&xs[k][tx * 8];
            float4 a1 = *(const float4*)&xs[k][tx * 8 + 4];
            float4 b0 = *(const float4*)&ws[k][ty * 8];
            float4 b1 = *(const float4*)&ws[k][ty * 8 + 4];
            float av[8] = {a0.x, a0.y, a0.z, a0.w, a1.x, a1.y, a1.z, a1.w};
            float bv[8] = {b0.x, b0.y, b0.z, b0.w, b1.x, b1.y, b1.z, b1.w};
#pragma unroll
            for (int i = 0; i < 8; ++i)
#pragma unroll
                for (int j = 0; j < 8; ++j)
                    acc[i][j] = fmaf(av[i], bv[j], acc[i][j]);
        }
        __syncthreads();
    }
#pragma unroll
    for (int i = 0; i < 8; ++i) {
        size_t tb = (size_t)tb_base + tx * 8 + i;
        float4 o0 = make_float4(acc[i][0], acc[i][1], acc[i][2], acc[i][3]);
        float4 o1 = make_float4(acc[i][4], acc[i][5], acc[i][6], acc[i][7]);
        *(float4*)&xwin[tb * HID + h_base + ty * 8]     = o0;
        *(float4*)&xwin[tb * HID + h_base + ty * 8 + 4] = o1;
    }
}

// ---------------- main scan: ONE WAVE per batch element, 8 neurons/lane ----------------
// neuron h = lane*8 + j  (j = slot 0..7); mask word j bit l <-> h = l*8 + j.
// No barriers, no LDS, no atomics: spike masks live in registers via __ballot.
__global__ __launch_bounds__(64)
void snn_scan1w(const float* __restrict__ xwin,              // [T][B][H]
                const float* __restrict__ wrT,               // [H][H], wrT[spk][h]
                unsigned long long* __restrict__ masks) {    // [T][B][8]
    const int b    = blockIdx.x;
    const int lane = threadIdx.x;
    const size_t hoff = (size_t)lane * 8;

    float v[8], ic[8], rho[8];
    unsigned long long m[8];
#pragma unroll
    for (int j = 0; j < 8; ++j) { v[j] = 0.f; ic[j] = 0.f; rho[j] = 0.f; m[j] = 0ull; }

    const float* xrow0 = &xwin[(size_t)b * HID + hoff];
    float4 xa = *(const float4*)xrow0;
    float4 xb = *(const float4*)(xrow0 + 4);

    for (int t = 0; t < T_STEPS; ++t) {
        // prefetch next step's input projection (hidden under this step)
        const int tn = (t + 1 < T_STEPS) ? t + 1 : t;
        const float* xnext = &xwin[((size_t)tn * BATCH + b) * HID + hoff];
        float4 xna = *(const float4*)xnext;
        float4 xnb = *(const float4*)(xnext + 4);

        // recurrent gather from previous-step spike masks (registers)
        float r[8];
#pragma unroll
        for (int j = 0; j < 8; ++j) r[j] = 0.f;
#pragma unroll
        for (int j = 0; j < 8; ++j) {
            unsigned long long mm = m[j];
            while (mm) {
                int l = (int)__builtin_ctzll(mm);
                mm &= mm - 1;
                const float* wp = &wrT[(size_t)(l * 8 + j) * HID + hoff];
                float4 wa = *(const float4*)wp;
                float4 wb = *(const float4*)(wp + 4);
                r[0] += wa.x; r[1] += wa.y; r[2] += wa.z; r[3] += wa.w;
                r[4] += wb.x; r[5] += wb.y; r[6] += wb.z; r[7] += wb.w;
            }
        }

        const float xi[8] = {xa.x, xa.y, xa.z, xa.w, xb.x, xb.y, xb.z, xb.w};
        float z[8];
#pragma unroll
        for (int j = 0; j < 8; ++j) {
            const float v_dec = v[j] + 0.1f * ((0.0f - v[j]) + ic[j]);
            const float i_dec = ic[j] * 0.8f;
            float zz     = (v_dec - 1.0f) > 0.0f ? 1.0f : 0.0f;
            float v_tmp  = (zz != 0.0f) ? 0.0f : v_dec;
            const float refr = (rho[j] > 0.0f) ? 1.0f : 0.0f;
            v[j]   = (refr != 0.0f) ? v[j] : v_tmp;
            zz     = (refr != 0.0f) ? 0.0f : zz;
            rho[j] = (zz != 0.0f) ? 5.0f : fmaxf(rho[j] - refr, 0.0f);
            ic[j]  = (i_dec + xi[j]) + r[j];
            z[j]   = zz;
        }
#pragma unroll
        for (int j = 0; j < 8; ++j) m[j] = __ballot(z[j] != 0.0f);

        if (lane == 0) {
            unsigned long long* mg = &masks[((size_t)t * BATCH + b) * 8];
#pragma unroll
            for (int j = 0; j < 8; ++j) mg[j] = m[j];
        }
        xa = xna; xb = xnb;
    }
}

// ---------------- readout pass 1: lin[t][b][o] = sum_spikes woutT[h][o] ----------------
// woutT staged in LDS with XOR swizzle (o' = o ^ ((h&7)<<2)) to spread banks.
__global__ __launch_bounds__(256)
void readout_lin(const unsigned long long* __restrict__ masks, // [T][B][8]
                 const float* __restrict__ woutT,              // [H][O]
                 float* __restrict__ lin) {                    // [T][B][O]
    __shared__ float s_w[HID * NOUT];
    const int tid = threadIdx.x;
#pragma unroll
    for (int q = 0; q < 16; ++q) {
        int fi = (q * 256 + tid) * 4;           // float index into [H][O]
        int h = fi >> 5, o = fi & 31;           // o is 4-aligned
        float4 w = *(const float4*)&woutT[fi];
        int xs = (h & 7) << 2;
        *(float4*)&s_w[(h << 5) + (o ^ xs)] = w;
    }
    __syncthreads();

    const int b  = blockIdx.y;
    const int t  = blockIdx.x * 64 + (tid & 63);
    const int o0 = (tid >> 6) * 8;
    if (t >= T_STEPS) return;

    const unsigned long long* mp = &masks[((size_t)t * BATCH + b) * 8];
    float a0 = 0.f, a1 = 0.f, a2 = 0.f, a3 = 0.f, a4 = 0.f, a5 = 0.f, a6 = 0.f, a7 = 0.f;
#pragma unroll
    for (int j = 0; j < 8; ++j) {
        unsigned long long mm = mp[j];
        while (mm) {
            int l = (int)__builtin_ctzll(mm);
            mm &= mm - 1;
            int h  = l * 8 + j;                 // matches scan kernel's mapping
            int xs = (h & 7) << 2;
            const float4 w0 = *(const float4*)&s_w[(h << 5) + (o0 ^ xs)];
            const float4 w1 = *(const float4*)&s_w[(h << 5) + ((o0 + 4) ^ xs)];
            a0 += w0.x; a1 += w0.y; a2 += w0.z; a3 += w0.w;
            a4 += w1.x; a5 += w1.y; a6 += w1.z; a7 += w1.w;
        }
    }
    float* op = &lin[((size_t)t * BATCH + b) * NOUT + o0];
    *(float4*)op       = make_float4(a0, a1, a2, a3);
    *(float4*)(op + 4) = make_float4(a4, a5, a6, a7);
}

// ---------------- readout pass 2: IIR filter, chunk-parallel with warmup ----------------
// o[t] = (1-a) o[t-1] + a lin[t];  (1-a)^128 ~ 1e-14 -> 128-step warmup makes
// each 125-step chunk independent to fp32 precision.
__global__ __launch_bounds__(256)
void readout_filter(const float* __restrict__ lin,   // [T][B*O]
                    const float* __restrict__ b_out,
                    float* __restrict__ out) {       // [T][B*O]
    const int bo = blockIdx.x * 256 + threadIdx.x;   // 0..2047
    const int c  = blockIdx.y;                       // chunk 0..7
    const float bb = b_out[bo & 31];
    const int t0 = c * 125;
    int ts = t0 - 128; if (ts < 0) ts = 0;
    const int te = t0 + 125;
    float o = 0.f;
    for (int t = ts; t < te; ++t) {
        float l = lin[(size_t)t * (BATCH * NOUT) + bo] + bb;
        o = o + ALPHA_F * (l - o);
        if (t >= t0) out[(size_t)t * (BATCH * NOUT) + bo] = o;
    }
}

// ---------------- legacy fallback (small-ws paths) ----------------
template<int PRECOMP>
__global__ __launch_bounds__(512)
void snn_main(const float* __restrict__ xsrc,
              const float* __restrict__ w_in,
              const float* __restrict__ wr, int wrA, int wrB,
              const float* __restrict__ wo, int woA, int woB,
              const float* __restrict__ b_out,
              float* __restrict__ out) {
    const int b    = blockIdx.x;
    const int tid  = threadIdx.x;
    const int lane = tid & 63;

    __shared__ int   s_list[2][HID];
    __shared__ int   s_cnt[2];
    __shared__ float s_xrow[2][FIN];

    if (tid < 2) s_cnt[tid] = 0;
    if (!PRECOMP && tid < FIN)
        s_xrow[0][tid] = xsrc[(size_t)b * FIN + tid];
    float iin_reg = 0.f;
    if (PRECOMP) iin_reg = xsrc[(size_t)b * HID + tid];
    __syncthreads();

    float v = 0.f, ic = 0.f, rho = 0.f, o_state = 0.f;
    const float bout_v = (tid < NOUT) ? b_out[tid] : 0.f;

    for (int t = 0; t < T_STEPS; ++t) {
        const int cur = t & 1, nxt = cur ^ 1;
        float iin_next = 0.f;
        if (PRECOMP) {
            int tn = (t + 1 < T_STEPS) ? (t + 1) : t;
            iin_next = xsrc[((size_t)tn * BATCH + b) * HID + tid];
        }
        float iin;
        if (PRECOMP) {
            iin = iin_reg;
        } else {
            float s0 = 0.f, s1 = 0.f, s2 = 0.f, s3 = 0.f;
#pragma unroll
            for (int kq = 0; kq < FIN / 4; ++kq) {
                float4 xv = *(const float4*)&s_xrow[cur][kq * 4];
                float4 wv = *(const float4*)&w_in[(size_t)tid * FIN + kq * 4];
                s0 = fmaf(xv.x, wv.x, s0); s1 = fmaf(xv.y, wv.y, s1);
                s2 = fmaf(xv.z, wv.z, s2); s3 = fmaf(xv.w, wv.w, s3);
            }
            iin = (s0 + s1) + (s2 + s3);
        }
        const int cn = s_cnt[cur];
        float r0 = 0.f, r1 = 0.f, r2 = 0.f, r3 = 0.f;
        int k = 0;
        for (; k + 4 <= cn; k += 4) {
            int i0 = s_list[cur][k],     i1 = s_list[cur][k + 1];
            int i2 = s_list[cur][k + 2], i3 = s_list[cur][k + 3];
            r0 += wr[(size_t)i0 * wrA + (size_t)tid * wrB];
            r1 += wr[(size_t)i1 * wrA + (size_t)tid * wrB];
            r2 += wr[(size_t)i2 * wrA + (size_t)tid * wrB];
            r3 += wr[(size_t)i3 * wrA + (size_t)tid * wrB];
        }
        for (; k < cn; ++k)
            r0 += wr[(size_t)s_list[cur][k] * wrA + (size_t)tid * wrB];
        const float rec = (r0 + r1) + (r2 + r3);

        const float v_dec = v + 0.1f * ((0.0f - v) + ic);
        const float i_dec = ic * 0.8f;
        float z      = (v_dec - 1.0f) > 0.0f ? 1.0f : 0.0f;
        float v_tmp  = (z != 0.0f) ? 0.0f : v_dec;
        const float refr = (rho > 0.0f) ? 1.0f : 0.0f;
        v   = (refr != 0.0f) ? v : v_tmp;
        z   = (refr != 0.0f) ? 0.0f : z;
        rho = (z != 0.0f) ? 5.0f : fmaxf(rho - refr, 0.0f);
        ic  = (i_dec + iin) + rec;

        unsigned long long mbal = __ballot(z != 0.0f);
        int nsp = __popcll(mbal);
        int base = 0;
        if (lane == 0 && nsp) base = atomicAdd(&s_cnt[nxt], nsp);
        base = __shfl(base, 0);
        if (z != 0.0f) {
            int pos = base + __popcll(mbal & ((1ull << lane) - 1ull));
            s_list[nxt][pos] = tid;
        }
        __syncthreads();

        if (tid < NOUT) {
            const int c2 = s_cnt[nxt];
            float lin = 0.f;
            for (int kk = 0; kk < c2; ++kk)
                lin += wo[(size_t)s_list[nxt][kk] * woA + (size_t)tid * woB];
            lin += bout_v;
            o_state = o_state + ALPHA_F * (lin - o_state);
            out[((size_t)t * BATCH + b) * NOUT + tid] = o_state;
        }
        if (tid == 0) s_cnt[cur] = 0;
        if (PRECOMP) iin_reg = iin_next;
        if (!PRECOMP && tid >= 128 && tid < 128 + FIN) {
            int tn = (t + 1 < T_STEPS) ? (t + 1) : t;
            s_xrow[nxt][tid - 128] = xsrc[((size_t)tn * BATCH + b) * FIN + (tid - 128)];
        }
        __syncthreads();
    }
}

extern "C" void kernel_launch(void* const* d_in, const int* in_sizes, int n_in,
                              void* d_out, int out_size, void* d_ws, size_t ws_size,
                              hipStream_t stream) {
    const float* x     = (const float*)d_in[0];
    const float* w_in  = (const float*)d_in[1];
    const float* w_rec = (const float*)d_in[2];
    const float* w_out = (const float*)d_in[3];
    const float* b_out = (const float*)d_in[4];
    float* out = (float*)d_out;

    const size_t xwin_b  = (size_t)T_STEPS * BATCH * HID * sizeof(float);   // 131.072 MB
    const size_t masks_b = (size_t)T_STEPS * BATCH * 8 * sizeof(unsigned long long); // 4.096 MB
    const size_t wrect_b = (size_t)HID * HID * sizeof(float);               // 1 MB
    const size_t woutt_b = (size_t)HID * NOUT * sizeof(float);              // 64 KB

    char* ws = (char*)d_ws;

    if (ws_size >= xwin_b + masks_b + wrect_b + woutt_b) {
        // new path: scan emits spike masks; readout reconstructed afterwards.
        float* xwin  = (float*)ws;                       // dead after scan
        float* lin   = (float*)ws;                       // overlays xwin
        unsigned long long* masks = (unsigned long long*)(ws + xwin_b);
        float* wrecT = (float*)(ws + xwin_b + masks_b);
        float* woutT = (float*)(ws + xwin_b + masks_b + wrect_b);

        prep_transpose<<<(HID * HID + 255) / 256, 256, 0, stream>>>(w_rec, w_out, wrecT, woutT);
        dim3 g(T_STEPS * BATCH / GTM, HID / GTN);
        xwin_gemm<<<g, 256, 0, stream>>>(x, w_in, xwin);
        snn_scan1w<<<BATCH, 64, 0, stream>>>(xwin, wrecT, masks);
        readout_lin<<<dim3((T_STEPS + 63) / 64, BATCH), 256, 0, stream>>>(masks, woutT, lin);
        readout_filter<<<dim3(BATCH * NOUT / 256, 8), 256, 0, stream>>>(lin, b_out, out);
    } else if (ws_size >= xwin_b + wrect_b + woutt_b) {
        float* xwin  = (float*)ws;
        float* wrecT = (float*)(ws + xwin_b);
        float* woutT = (float*)(ws + xwin_b + wrect_b);
        prep_transpose<<<(HID * HID + 255) / 256, 256, 0, stream>>>(w_rec, w_out, wrecT, woutT);
        dim3 g(T_STEPS * BATCH / GTM, HID / GTN);
        xwin_gemm<<<g, 256, 0, stream>>>(x, w_in, xwin);
        snn_main<1><<<BATCH, HID, 0, stream>>>(xwin, nullptr, wrecT, HID, 1,
                                               woutT, NOUT, 1, b_out, out);
    } else if (ws_size >= wrect_b + woutt_b) {
        float* wrecT = (float*)ws;
        float* woutT = (float*)(ws + wrect_b);
        prep_transpose<<<(HID * HID + 255) / 256, 256, 0, stream>>>(w_rec, w_out, wrecT, woutT);
        snn_main<0><<<BATCH, HID, 0, stream>>>(x, w_in, wrecT, HID, 1,
                                               woutT, NOUT, 1, b_out, out);
    } else {
        snn_main<0><<<BATCH, HID, 0, stream>>>(x, w_in, w_rec, 1, HID,
                                               w_out, 1, HID, b_out, out);
    }
}